// Round 4
// baseline (518.342 us; speedup 1.0000x reference)
//
#include <hip/hip_runtime.h>
#include <math.h>

#define NNZ_C 3200000
#define NN_C  100000
#define NE_C  100000
#define KD    16
#define EPSF  1e-6f
#define LSEP  0.1f

typedef unsigned int uint_t;

// ---------- Path A workspace layout (word offsets), total ~41.4 MB ----------
//   [0, 50000)        packed degree counters (u32, 4x8-bit bins)      (zeroed)
//   [50000, 50128)    bucket cursors (100 used)                       (zeroed)
//   [50128, 50192)    acc: theta[0..15], fdvf[16..31], sep[32..35]    (zeroed)
//   [50192, +100000)  Dv (fully written)
//   [150192, +100000) De (fully written)
//   [250192, +100*36864) bucket records (u32)
//   [3936592, +400*16000) S slice partials (fully written)
#define A_PK    0
#define A_CUR   50000
#define A_ACC   50128
#define A_DV    50192
#define A_DE    150192
#define A_REC   250192
#define RCAP    36864
#define A_PART  (A_REC + 100 * RCAP)
#define A_END   (A_PART + 400 * 16000)
#define A_ZERO  50192

// ---------- Path B (fallback, round-3 proven, ~7.4 MB) ----------------------
#define B_PK    0
#define B_ACC   50000
#define B_S     50064
#define B_DV    (B_S + NE_C * KD)
#define B_DE    (B_DV + NN_C)
#define B_ZERO  B_DV

// ---- K1: degree histograms, LDS byte-packed, 512 thr + int4 loads ----------
__global__ __launch_bounds__(512) void k_hist(const int* __restrict__ il,
                                              uint_t* __restrict__ packed) {
    __shared__ uint_t h[12500];
    int t = threadIdx.x, b = blockIdx.x;
    int hist  = b >> 7;          // 0 -> node (Dv), 1 -> edge (De)
    int range = (b >> 6) & 1;    // bins [range*50000, +50000)
    int slice = b & 63;          // contiguous 50K-pin slice

    for (int w = t; w < 12500; w += 512) h[w] = 0u;
    __syncthreads();

    const int4* idx4 = (const int4*)(il + (size_t)hist * NNZ_C + (size_t)slice * 50000);
    uint_t base = (uint_t)range * 50000u;
    for (int i = t; i < 12500; i += 512) {
        int4 v = idx4[i];
        uint_t u;
        u = (uint_t)v.x - base; if (u < 50000u) atomicAdd(&h[u >> 2], 1u << ((u & 3u) * 8u));
        u = (uint_t)v.y - base; if (u < 50000u) atomicAdd(&h[u >> 2], 1u << ((u & 3u) * 8u));
        u = (uint_t)v.z - base; if (u < 50000u) atomicAdd(&h[u >> 2], 1u << ((u & 3u) * 8u));
        u = (uint_t)v.w - base; if (u < 50000u) atomicAdd(&h[u >> 2], 1u << ((u & 3u) * 8u));
    }
    __syncthreads();

    uint_t* gp = packed + hist * 25000 + range * 12500;
    for (int w = t; w < 12500; w += 512) {
        uint_t v = h[w];
        if (v) atomicAdd(&gp[w], v);   // coalesced consecutive words
    }
}

// ---- K2: unpack byte counters -> float Dv, De ------------------------------
__global__ __launch_bounds__(256) void k_unpack(const uint_t* __restrict__ packed,
                                                float* __restrict__ Dv,
                                                float* __restrict__ De) {
    int w = blockIdx.x * 256 + threadIdx.x;
    if (w < 50000) {
        uint_t v = packed[w];
        float4 f = make_float4((float)(v & 255u), (float)((v >> 8) & 255u),
                               (float)((v >> 16) & 255u), (float)(v >> 24));
        float* dst = (w < 25000) ? (Dv + (size_t)w * 4) : (De + (size_t)(w - 25000) * 4);
        *(float4*)dst = f;
    }
}

// ---- K3: f_Dv_f partials + separation stats --------------------------------
__global__ __launch_bounds__(256) void k_norm(const float* __restrict__ Z,
                                              const float* __restrict__ Dv,
                                              float* __restrict__ acc) {
    __shared__ float sacc[KD + 4];
    int t = threadIdx.x;
    if (t < KD + 4) sacc[t] = 0.f;
    __syncthreads();

    int n = blockIdx.x * 256 + t;
    if (n < NN_C) {
        float dv = fmaxf(Dv[n], EPSF);
        const float4* z4 = (const float4*)(Z + (size_t)n * KD);
        float zr[KD];
        #pragma unroll
        for (int i = 0; i < 4; ++i) {
            float4 z = z4[i];
            zr[4*i+0] = z.x; zr[4*i+1] = z.y; zr[4*i+2] = z.z; zr[4*i+3] = z.w;
        }
        #pragma unroll
        for (int k = 0; k < KD; ++k) atomicAdd(&sacc[k], zr[k] * zr[k] * dv);
        float f = zr[0];
        if (f > 0.f)      { atomicAdd(&sacc[KD+0], f); atomicAdd(&sacc[KD+2], 1.f); }
        else if (f < 0.f) { atomicAdd(&sacc[KD+1], f); atomicAdd(&sacc[KD+3], 1.f); }
    }
    __syncthreads();
    if (t < KD)          atomicAdd(&acc[16 + t], sacc[t]);
    else if (t < KD + 4) atomicAdd(&acc[32 + (t - KD)], sacc[t]);
}

// ---- K4a: bucket pins by edge/1000 into packed u32 records ------------------
__global__ __launch_bounds__(256) void k_bucket(const int* __restrict__ il,
                                                uint_t* __restrict__ cur,
                                                uint_t* __restrict__ recs) {
    __shared__ uint_t cnt[100], bas[100];
    int t = threadIdx.x;
    for (int i = t; i < 100; i += 256) cnt[i] = 0u;
    __syncthreads();

    int base = blockIdx.x * 4096;
    uint_t myrec[16], mybl[16];
    #pragma unroll
    for (int i = 0; i < 16; ++i) {
        int p = base + i * 256 + t;
        myrec[i] = 0xFFFFFFFFu;
        if (p < NNZ_C) {
            uint_t n = (uint_t)il[p];
            uint_t e = (uint_t)il[NNZ_C + p];
            uint_t bkt = e / 1000u;
            uint_t el  = e - bkt * 1000u;
            uint_t slot = atomicAdd(&cnt[bkt], 1u);
            myrec[i] = (n << 10) | el;
            mybl[i]  = (bkt << 16) | slot;
        }
    }
    __syncthreads();
    for (int i = t; i < 100; i += 256) bas[i] = atomicAdd(&cur[i], cnt[i]);
    __syncthreads();
    #pragma unroll
    for (int i = 0; i < 16; ++i) {
        if (myrec[i] != 0xFFFFFFFFu) {
            uint_t bkt = mybl[i] >> 16, slot = mybl[i] & 0xFFFFu;
            uint_t pos = bas[bkt] + slot;
            if (pos < RCAP) recs[(size_t)bkt * RCAP + pos] = myrec[i];
        }
    }
}

// ---- K4b: per-bucket LDS accumulation of S slice partials -------------------
// block = bucket*4 + slice; 1000-edge S-subtile in LDS, XOR-swizzled rows.
__global__ __launch_bounds__(512) void k_scan(const uint_t* __restrict__ recs,
                                              const uint_t* __restrict__ cur,
                                              const float* __restrict__ Z,
                                              const float* __restrict__ Dv,
                                              float* __restrict__ part) {
    __shared__ float Ss[16000];          // 62.5 KB
    int t = threadIdx.x;
    int bkt = blockIdx.x >> 2, s = blockIdx.x & 3;

    for (int i = t; i < 4000; i += 512) ((float4*)Ss)[i] = make_float4(0.f, 0.f, 0.f, 0.f);
    __syncthreads();

    uint_t c = cur[bkt];
    if (c > RCAP) c = RCAP;
    uint_t lo = (c * (uint_t)s) >> 2, hi = (c * (uint_t)(s + 1)) >> 2;
    const uint_t* r = recs + (size_t)bkt * RCAP;
    for (uint_t i = lo + t; i < hi; i += 512) {
        uint_t rc = r[i];
        uint_t n  = rc >> 10, el = rc & 1023u;
        float inv = rsqrtf(fmaxf(Dv[n], EPSF));
        const float4* z4 = (const float4*)(Z + (size_t)n * KD);
        float* dst = &Ss[el * 16];
        uint_t sw = el & 15u;
        #pragma unroll
        for (int j = 0; j < 4; ++j) {
            float4 z = z4[j];
            atomicAdd(&dst[(4*j+0) ^ sw], z.x * inv);
            atomicAdd(&dst[(4*j+1) ^ sw], z.y * inv);
            atomicAdd(&dst[(4*j+2) ^ sw], z.z * inv);
            atomicAdd(&dst[(4*j+3) ^ sw], z.w * inv);
        }
    }
    __syncthreads();

    float* gp = part + (size_t)blockIdx.x * 16000;
    for (int i = t; i < 4000; i += 512) ((float4*)gp)[i] = ((float4*)Ss)[i];
}

// ---- K4c: theta[k] = sum_e (sum_s part)^2 / De[e]  (swizzle-aware read) -----
__global__ __launch_bounds__(256) void k_rtheta(const float* __restrict__ part,
                                                const float* __restrict__ De,
                                                float* __restrict__ acc) {
    __shared__ float sacc[KD];
    int t = threadIdx.x;
    if (t < KD) sacc[t] = 0.f;
    __syncthreads();

    uint_t gid = blockIdx.x * 256u + t;
    if (gid < (uint_t)NE_C * KD) {
        uint_t e = gid >> 4, k = gid & 15u;
        uint_t b = e / 1000u, el = e - b * 1000u;
        uint_t pos = el * 16u + (k ^ (el & 15u));
        const float* p0 = part + (size_t)b * 4 * 16000 + pos;
        float sv = p0[0] + p0[16000] + p0[32000] + p0[48000];
        float rinv = 1.f / fmaxf(De[e], EPSF);
        atomicAdd(&sacc[k], sv * sv * rinv);
    }
    __syncthreads();
    if (t < KD) atomicAdd(&acc[t], sacc[t]);
}

// ---- Fallback: round-3 scatter + theta --------------------------------------
__global__ __launch_bounds__(256) void k_scatter(const int* __restrict__ il,
                                                 const float* __restrict__ Z,
                                                 const float* __restrict__ Dv,
                                                 float* __restrict__ S) {
    uint_t tid = blockIdx.x * 256u + threadIdx.x;
    if (tid < (uint_t)NNZ_C * KD) {
        int p = (int)(tid >> 4);
        int k = (int)(tid & 15u);
        int n = il[p];
        int e = il[NNZ_C + p];
        float inv = rsqrtf(fmaxf(Dv[n], EPSF));
        float v = Z[(size_t)n * KD + k] * inv;
        atomicAdd(&S[(size_t)e * KD + k], v);
    }
}

__global__ __launch_bounds__(256) void k_theta(const float* __restrict__ S,
                                               const float* __restrict__ De,
                                               float* __restrict__ acc) {
    __shared__ float sacc[KD];
    int t = threadIdx.x;
    if (t < KD) sacc[t] = 0.f;
    __syncthreads();
    int e = blockIdx.x * 256 + t;
    if (e < NE_C) {
        float rinv = 1.f / fmaxf(De[e], EPSF);
        const float4* s4 = (const float4*)(S + (size_t)e * KD);
        #pragma unroll
        for (int i = 0; i < 4; ++i) {
            float4 s = s4[i];
            atomicAdd(&sacc[4*i+0], s.x * s.x * rinv);
            atomicAdd(&sacc[4*i+1], s.y * s.y * rinv);
            atomicAdd(&sacc[4*i+2], s.z * s.z * rinv);
            atomicAdd(&sacc[4*i+3], s.w * s.w * rinv);
        }
    }
    __syncthreads();
    if (t < KD) atomicAdd(&acc[t], sacc[t]);
}

// ---- K5: finalize ------------------------------------------------------------
__global__ void k_final(const float* __restrict__ acc, float* __restrict__ out) {
    if (blockIdx.x == 0 && threadIdx.x == 0) {
        float rsum = 0.f;
        #pragma unroll
        for (int k = 0; k < KD; ++k) {
            float theta = acc[k];
            float fd    = fmaxf(acc[16 + k], EPSF);
            float rq    = 1.f - theta / fd;
            if (!isfinite(rq)) rq = 0.f;
            rsum += rq;
        }
        float rl = rsum / (float)KD;
        float pS = acc[32], nS = acc[33], pC = acc[34], nC = acc[35];
        float pm = pS / fmaxf(pC, 1.f);
        float nm = nS / fmaxf(nC, 1.f);
        float sep = fabsf(pm - nm);
        float pen = (pC == 0.f || nC == 0.f) ? 1.f : 1.f / (sep + EPSF);
        out[0] = rl + LSEP * pen;
    }
}

extern "C" void kernel_launch(void* const* d_in, const int* in_sizes, int n_in,
                              void* d_out, int out_size, void* d_ws, size_t ws_size,
                              hipStream_t stream) {
    const float* Z  = (const float*)d_in[0];
    const int*   il = (const int*)d_in[1];   // (2, NNZ) int32
    float*  ws     = (float*)d_ws;
    uint_t* packed = (uint_t*)d_ws;
    float*  out    = (float*)d_out;

    if (ws_size >= (size_t)(A_END + 256) * sizeof(float)) {
        // ---------------- Path A: bucketed LDS aggregation ----------------
        uint_t* cur  = (uint_t*)d_ws + A_CUR;
        float*  acc  = ws + A_ACC;
        float*  Dv   = ws + A_DV;
        float*  De   = ws + A_DE;
        uint_t* recs = (uint_t*)d_ws + A_REC;
        float*  part = ws + A_PART;

        hipMemsetAsync(ws, 0, (size_t)A_ZERO * sizeof(float), stream);
        k_hist  <<<256, 512, 0, stream>>>(il, packed);
        k_unpack<<<(50000 + 255) / 256, 256, 0, stream>>>(packed, Dv, De);
        k_norm  <<<(NN_C + 255) / 256, 256, 0, stream>>>(Z, Dv, acc);
        k_bucket<<<(NNZ_C + 4095) / 4096, 256, 0, stream>>>(il, cur, recs);
        k_scan  <<<400, 512, 0, stream>>>(recs, cur, Z, Dv, part);
        k_rtheta<<<(NE_C * KD + 255) / 256, 256, 0, stream>>>(part, De, acc);
        k_final <<<1, 64, 0, stream>>>(acc, out);
    } else {
        // ---------------- Path B: proven round-3 pipeline -----------------
        float* acc = ws + B_ACC;
        float* S   = ws + B_S;
        float* Dv  = ws + B_DV;
        float* De  = ws + B_DE;

        hipMemsetAsync(ws, 0, (size_t)B_ZERO * sizeof(float), stream);
        k_hist  <<<256, 512, 0, stream>>>(il, packed);
        k_unpack<<<(50000 + 255) / 256, 256, 0, stream>>>(packed, Dv, De);
        k_norm  <<<(NN_C + 255) / 256, 256, 0, stream>>>(Z, Dv, acc);
        {
            uint_t total = (uint_t)NNZ_C * KD;
            k_scatter<<<(total + 255) / 256, 256, 0, stream>>>(il, Z, Dv, S);
        }
        k_theta <<<(NE_C + 255) / 256, 256, 0, stream>>>(S, De, acc);
        k_final <<<1, 64, 0, stream>>>(acc, out);
    }
}